// Round 2
// baseline (398.829 us; speedup 1.0000x reference)
//
#include <hip/hip_runtime.h>
#include <hip/hip_bf16.h>

typedef __attribute__((ext_vector_type(8))) short bf16x8;
typedef __attribute__((ext_vector_type(4))) float f32x4;

#define D 128
#define K1 256

static __device__ __forceinline__ ushort f2bf(float f) {
    unsigned u = __float_as_uint(f);
    unsigned r = (u + 0x7fffu + ((u >> 16) & 1u)) >> 16;
    return (ushort)r;
}
static __device__ __forceinline__ float bf2f(ushort h) {
    return __uint_as_float(((unsigned)h) << 16);
}

// ---------- prep: x->bf16, W1->W1^T bf16 [128][256], W2->W2^T bf16 [128][128], + col histogram
__global__ void prep_kernel(const float* __restrict__ x,
                            const float* __restrict__ W1,
                            const float* __restrict__ W2,
                            const int* __restrict__ ecol,
                            ushort* __restrict__ xbf,
                            ushort* __restrict__ w1t,
                            ushort* __restrict__ w2t,
                            int* __restrict__ hist,
                            int n_x4, int E, int n_nodes)
{
    int gid = blockIdx.x * blockDim.x + threadIdx.x;
    if (gid < n_x4) {
        float4 v = ((const float4*)x)[gid];
        ushort4 o;
        o.x = f2bf(v.x); o.y = f2bf(v.y); o.z = f2bf(v.z); o.w = f2bf(v.w);
        ((ushort4*)xbf)[gid] = o;
    } else {
        int wid = gid - n_x4;
        if (wid < K1 * D) {
            int n = wid >> 8;
            int k = wid & 255;
            w1t[wid] = f2bf(W1[k * D + n]);
        } else if (wid < K1 * D + D * D) {
            int id2 = wid - K1 * D;
            int n = id2 >> 7;
            int k = id2 & 127;
            w2t[id2] = f2bf(W2[k * D + n]);
        } else {
            int e = wid - (K1 * D + D * D);
            if (e < E) {
                int c = ecol[e];
                if ((unsigned)c >= (unsigned)n_nodes) c = 0;
                atomicAdd(&hist[c], 1);
            }
        }
    }
}

// ---------- exclusive scan of hist (single block, 1024 threads)
__global__ __launch_bounds__(1024) void scan_kernel(const int* __restrict__ hist,
                                                    int* __restrict__ ofs, int N)
{
    __shared__ int part[1024];
    const int tid = threadIdx.x;
    const int chunk = (N + 1023) >> 10;
    int begin = tid * chunk;
    int end = begin + chunk; if (end > N) end = N;
    int s = 0;
    for (int i = begin; i < end; ++i) s += hist[i];
    part[tid] = s;
    __syncthreads();
    for (int off = 1; off < 1024; off <<= 1) {
        int v = (tid >= off) ? part[tid - off] : 0;
        __syncthreads();
        part[tid] += v;
        __syncthreads();
    }
    int run = (tid > 0) ? part[tid - 1] : 0;
    for (int i = begin; i < end; ++i) {
        int h = hist[i];
        ofs[i] = run;
        run += h;
    }
}

// ---------- scatter: sorted-by-col edge id list (counting sort, unstable; max is order-indep)
__global__ void scatter_kernel(const int* __restrict__ ecol,
                               int* __restrict__ ofs,
                               int* __restrict__ sorted_e,
                               int E, int n_nodes)
{
    int e = blockIdx.x * blockDim.x + threadIdx.x;
    if (e < E) {
        int c = ecol[e];
        if ((unsigned)c >= (unsigned)n_nodes) c = 0;
        int pos = atomicAdd(&ofs[c], 1);
        sorted_e[pos] = e;
    }
}

// ---------- main fused kernel: 64 sorted edges per block, 256 threads (4 waves, 2x2)
__global__ __launch_bounds__(256) void edgeconv_main(
    const ushort* __restrict__ xbf,
    const ushort* __restrict__ w1t,
    const ushort* __restrict__ w2t,
    const float* __restrict__ b1,
    const float* __restrict__ b2,
    const int* __restrict__ erow,
    const int* __restrict__ ecol,
    const int* __restrict__ sorted_e,
    unsigned int* __restrict__ out_enc,
    int E, int n_nodes)
{
    __shared__ ushort A1[64 * 256];   // 32KB feat tile; reused as float M[64][128] after layer2
    __shared__ ushort Hs[64 * 128];   // 16KB h tile
    __shared__ int colidx[64];
    __shared__ int rowidx[64];
    __shared__ unsigned char starts[64];
    __shared__ int nruns_s, nvalid_s;

    const int tid = threadIdx.x;

    // XCD-bijective swizzle: consecutive work ids -> same XCD (sorted cols share L2)
    const int nwg = gridDim.x;
    const int orig = blockIdx.x;
    const int q = nwg >> 3, rr = nwg & 7;
    const int xcd = orig & 7;
    const int wgid = (xcd < rr ? xcd * (q + 1) : rr * (q + 1) + (xcd - rr) * q) + (orig >> 3);
    const int e0 = wgid * 64;

    if (tid < 64) {
        int idx = e0 + tid;
        int eid = (idx < E) ? sorted_e[idx] : -1;
        int c = -1, r0 = 0;
        if (eid >= 0) {
            c = ecol[eid]; if ((unsigned)c >= (unsigned)n_nodes) c = 0;
            r0 = erow[eid]; if ((unsigned)r0 >= (unsigned)n_nodes) r0 = 0;
        }
        colidx[tid] = c;
        rowidx[tid] = r0;
    }
    __syncthreads();

    // run detection over sorted colidx (wave 0 only)
    if (tid < 64) {
        int r = tid;
        int c = colidx[r];
        bool valid = (c >= 0);
        bool isStart = valid && (r == 0 || colidx[r - 1] != c);
        unsigned long long mb = __ballot(isStart);
        unsigned long long vb = __ballot(valid);
        if (r == 0) { nruns_s = __popcll(mb); nvalid_s = __popcll(vb); }
        if (isStart) {
            int pos = __popcll(mb & ((1ull << r) - 1ull));
            starts[pos] = (unsigned char)r;
        }
    }

    // ---- gather: feat[e][0:128]=x[col], feat[e][128:256]=x[row]-x[col]
    {
        const int l16 = tid & 15;
        const int eg  = tid >> 4;
        #pragma unroll
        for (int it = 0; it < 4; ++it) {
            int e = it * 16 + eg;
            int nc = colidx[e]; if (nc < 0) nc = 0;
            int nr = rowidx[e];
            bf16x8 vc = *(const bf16x8*)(xbf + (size_t)nc * D + l16 * 8);
            bf16x8 vr = *(const bf16x8*)(xbf + (size_t)nr * D + l16 * 8);
            bf16x8 vd;
            #pragma unroll
            for (int j = 0; j < 8; ++j) {
                float fc = bf2f((ushort)vc[j]);
                float fr = bf2f((ushort)vr[j]);
                vd[j] = (short)f2bf(fr - fc);
            }
            char* base = (char*)A1 + e * 512;
            const int sw = (e & 7) << 4;
            *(bf16x8*)(base + ((l16 * 16) ^ sw))         = vc;
            *(bf16x8*)(base + (((256 + l16 * 16)) ^ sw)) = vd;
        }
    }
    __syncthreads();

    const int l   = tid & 63;
    const int w   = tid >> 6;
    const int wr  = w >> 1, wc = w & 1;
    const int l15 = l & 15;
    const int lq  = l >> 4;
    const int mr  = wr * 32;

    // ---- layer 1: [64x256] @ [256x128] -> h [64x128]
    f32x4 acc[2][4];
    #pragma unroll
    for (int mf = 0; mf < 2; ++mf)
        #pragma unroll
        for (int nf = 0; nf < 4; ++nf)
            acc[mf][nf] = (f32x4){0.f, 0.f, 0.f, 0.f};

    #pragma unroll
    for (int kk = 0; kk < 8; ++kk) {
        bf16x8 a[2], b[4];
        #pragma unroll
        for (int mf = 0; mf < 2; ++mf) {
            int row = mr + mf * 16 + l15;
            int kbyte = kk * 64 + lq * 16;
            a[mf] = *(const bf16x8*)((const char*)A1 + row * 512 + (kbyte ^ ((row & 7) << 4)));
        }
        #pragma unroll
        for (int nf = 0; nf < 4; ++nf) {
            int wcol = wc * 64 + nf * 16 + l15;
            b[nf] = *(const bf16x8*)(w1t + wcol * 256 + kk * 32 + lq * 8);
        }
        #pragma unroll
        for (int mf = 0; mf < 2; ++mf)
            #pragma unroll
            for (int nf = 0; nf < 4; ++nf)
                acc[mf][nf] = __builtin_amdgcn_mfma_f32_16x16x32_bf16(a[mf], b[nf], acc[mf][nf], 0, 0, 0);
    }

    // ---- epilogue 1: + b1, relu, -> Hs (bf16, swizzled)
    #pragma unroll
    for (int nf = 0; nf < 4; ++nf) {
        int col = wc * 64 + nf * 16 + l15;
        float bias = b1[col];
        #pragma unroll
        for (int mf = 0; mf < 2; ++mf) {
            #pragma unroll
            for (int r = 0; r < 4; ++r) {
                int row = mr + mf * 16 + lq * 4 + r;
                float v = acc[mf][nf][r] + bias;
                v = fmaxf(v, 0.f);
                *(ushort*)((char*)Hs + row * 256 + ((col * 2) ^ ((row & 7) << 4))) = f2bf(v);
            }
        }
    }
    __syncthreads();   // Hs ready; also: all A1 reads done -> M may overwrite A1 after this

    // ---- layer 2: [64x128] @ [128x128] -> msg [64x128]
    f32x4 acc2[2][4];
    #pragma unroll
    for (int mf = 0; mf < 2; ++mf)
        #pragma unroll
        for (int nf = 0; nf < 4; ++nf)
            acc2[mf][nf] = (f32x4){0.f, 0.f, 0.f, 0.f};

    #pragma unroll
    for (int kk = 0; kk < 4; ++kk) {
        bf16x8 a[2], b[4];
        #pragma unroll
        for (int mf = 0; mf < 2; ++mf) {
            int row = mr + mf * 16 + l15;
            int kbyte = kk * 64 + lq * 16;
            a[mf] = *(const bf16x8*)((const char*)Hs + row * 256 + (kbyte ^ ((row & 7) << 4)));
        }
        #pragma unroll
        for (int nf = 0; nf < 4; ++nf) {
            int wcol = wc * 64 + nf * 16 + l15;
            b[nf] = *(const bf16x8*)(w2t + wcol * 128 + kk * 32 + lq * 8);
        }
        #pragma unroll
        for (int mf = 0; mf < 2; ++mf)
            #pragma unroll
            for (int nf = 0; nf < 4; ++nf)
                acc2[mf][nf] = __builtin_amdgcn_mfma_f32_16x16x32_bf16(a[mf], b[nf], acc2[mf][nf], 0, 0, 0);
    }

    // ---- epilogue 2: + b2 -> M (f32, in A1's space, 2-way-swizzled)
    float* Mlds = (float*)A1;
    #pragma unroll
    for (int nf = 0; nf < 4; ++nf) {
        int col = wc * 64 + nf * 16 + l15;
        float bias = b2[col];
        #pragma unroll
        for (int mf = 0; mf < 2; ++mf) {
            #pragma unroll
            for (int r = 0; r < 4; ++r) {
                int row = mr + mf * 16 + lq * 4 + r;
                float v = acc2[mf][nf][r] + bias;
                *(float*)((char*)Mlds + row * 512 + ((col * 4) ^ ((row & 4) << 4))) = v;
            }
        }
    }
    __syncthreads();

    // ---- block-local segmented max over runs, one atomic per (run, col)
    {
        const int c  = tid & 127;
        const int g  = tid >> 7;
        const int nruns = nruns_s;
        const int nvalid = nvalid_s;
        for (int k = g; k < nruns; k += 2) {
            int s  = starts[k];
            int e_ = (k + 1 < nruns) ? (int)starts[k + 1] : nvalid;
            float m = -INFINITY;
            for (int r2 = s; r2 < e_; ++r2)
                m = fmaxf(m, *(const float*)((const char*)Mlds + r2 * 512 + ((c * 4) ^ ((r2 & 4) << 4))));
            int node = colidx[s];
            unsigned bs = __float_as_uint(m);
            unsigned enc = (bs & 0x80000000u) ? ~bs : (bs | 0x80000000u);
            atomicMax(&out_enc[(size_t)node * D + c], enc);
        }
    }
}

// ---------- decode: in-place on d_out; u==0 means empty segment -> 0.0f
__global__ void decode_kernel(unsigned int* __restrict__ io, int n4)
{
    int gid = blockIdx.x * blockDim.x + threadIdx.x;
    if (gid < n4) {
        uint4 u = ((const uint4*)io)[gid];
        float4 f;
        #define DEC(ux) ((ux) == 0u ? 0.f : (((ux) & 0x80000000u) ? __uint_as_float((ux) & 0x7fffffffu) : __uint_as_float(~(ux))))
        f.x = DEC(u.x); f.y = DEC(u.y); f.z = DEC(u.z); f.w = DEC(u.w);
        #undef DEC
        ((float4*)io)[gid] = f;
    }
}

extern "C" void kernel_launch(void* const* d_in, const int* in_sizes, int n_in,
                              void* d_out, int out_size, void* d_ws, size_t ws_size,
                              hipStream_t stream)
{
    const float* x  = (const float*)d_in[0];
    const int* eidx = (const int*)d_in[1];
    const float* W1 = (const float*)d_in[2];
    const float* b1 = (const float*)d_in[3];
    const float* W2 = (const float*)d_in[4];
    const float* b2 = (const float*)d_in[5];

    const int n_nodes = in_sizes[0] / D;
    const int E = in_sizes[1] / 2;
    const int* erow = eidx;        // edge_index[0]
    const int* ecol = eidx + E;    // edge_index[1]

    // workspace layout
    char* ws = (char*)d_ws;
    ushort* xbf = (ushort*)ws;
    ushort* w1t = xbf + (size_t)n_nodes * D;
    ushort* w2t = w1t + (size_t)K1 * D;
    size_t off = ((size_t)n_nodes * D + (size_t)K1 * D + (size_t)D * D) * sizeof(ushort);
    off = (off + 255) & ~(size_t)255;
    int* hist = (int*)(ws + off);          off += (size_t)n_nodes * 4;
    off = (off + 255) & ~(size_t)255;
    int* ofs = (int*)(ws + off);           off += (size_t)n_nodes * 4;
    off = (off + 255) & ~(size_t)255;
    int* sorted_e = (int*)(ws + off);      // E ints

    unsigned int* out_enc = (unsigned int*)d_out;

    hipMemsetAsync(d_out, 0, (size_t)out_size * sizeof(float), stream);
    hipMemsetAsync(hist, 0, (size_t)n_nodes * sizeof(int), stream);

    const int n_x4 = n_nodes * D / 4;
    const int prep_work = n_x4 + K1 * D + D * D + E;
    prep_kernel<<<(prep_work + 255) / 256, 256, 0, stream>>>(x, W1, W2, ecol, xbf, w1t, w2t, hist, n_x4, E, n_nodes);

    scan_kernel<<<1, 1024, 0, stream>>>(hist, ofs, n_nodes);

    scatter_kernel<<<(E + 255) / 256, 256, 0, stream>>>(ecol, ofs, sorted_e, E, n_nodes);

    const int nblocks = (E + 63) / 64;
    edgeconv_main<<<nblocks, 256, 0, stream>>>(xbf, w1t, w2t, b1, b2, erow, ecol, sorted_e, out_enc, E, n_nodes);

    const int n4 = out_size / 4;
    decode_kernel<<<(n4 + 255) / 256, 256, 0, stream>>>(out_enc, n4);
}

// Round 3
// 204.969 us; speedup vs baseline: 1.9458x; 1.9458x over previous
//
#include <hip/hip_runtime.h>
#include <hip/hip_bf16.h>

typedef __attribute__((ext_vector_type(8))) short bf16x8;
typedef __attribute__((ext_vector_type(4))) float f32x4;

#define D 128
#define NCH 256   // Pab channels: [0:128)=Pa, [128:256)=Pb

static __device__ __forceinline__ ushort f2bf(float f) {
    unsigned u = __float_as_uint(f);
    unsigned r = (u + 0x7fffu + ((u >> 16) & 1u)) >> 16;
    return (ushort)r;
}
static __device__ __forceinline__ float bf2f(ushort h) {
    return __uint_as_float(((unsigned)h) << 16);
}

// ---------- prep: w1abt[oc][k] (oc<128: W1a=W1top-W1bot; oc>=128: W1b), w2t[oc][k], col histogram
__global__ void prep_kernel(const float* __restrict__ W1,
                            const float* __restrict__ W2,
                            const int* __restrict__ ecol,
                            ushort* __restrict__ w1abt,
                            ushort* __restrict__ w2t,
                            int* __restrict__ hist,
                            int E, int n_nodes)
{
    int gid = blockIdx.x * blockDim.x + threadIdx.x;
    if (gid < NCH * D) {
        int oc = gid >> 7, k = gid & 127;
        float v;
        if (oc < 128) v = W1[k * D + oc] - W1[(k + 128) * D + oc];
        else          v = W1[(k + 128) * D + (oc - 128)];
        w1abt[gid] = f2bf(v);
    } else if (gid < NCH * D + D * D) {
        int id2 = gid - NCH * D;
        int oc = id2 >> 7, k = id2 & 127;
        w2t[id2] = f2bf(W2[k * D + oc]);
    } else {
        int e = gid - (NCH * D + D * D);
        if (e < E) {
            int c = ecol[e];
            if ((unsigned)c >= (unsigned)n_nodes) c = 0;
            atomicAdd(&hist[c], 1);
        }
    }
}

// ---------- Pab = x(bf16) @ [W1a | W1b] : per-node layer-1 partials, bf16 out
__global__ __launch_bounds__(256) void pab_kernel(
    const float* __restrict__ x,
    const ushort* __restrict__ w1abt,
    ushort* __restrict__ pab,
    int n_nodes)
{
    __shared__ ushort A[64 * 128];   // [node][k] bf16, swizzled
    const int tid = threadIdx.x;
    const int base = blockIdx.x * 64;

    #pragma unroll
    for (int it = 0; it < 8; ++it) {
        int idx4 = it * 256 + tid;       // float4 index in 64x128 tile
        int row = idx4 >> 5;
        int c4  = idx4 & 31;
        int node = base + row;
        float4 v = make_float4(0.f, 0.f, 0.f, 0.f);
        if (node < n_nodes) v = ((const float4*)x)[(size_t)node * 32 + c4];
        ushort4 o;
        o.x = f2bf(v.x); o.y = f2bf(v.y); o.z = f2bf(v.z); o.w = f2bf(v.w);
        *(ushort4*)((char*)A + row * 256 + ((c4 * 8) ^ ((row & 7) << 4))) = o;
    }
    __syncthreads();

    const int l = tid & 63, w = tid >> 6;
    const int l15 = l & 15, lq = l >> 4;

    f32x4 acc[4][4];                 // [channel frag][node frag]
    #pragma unroll
    for (int cf = 0; cf < 4; ++cf)
        #pragma unroll
        for (int rf = 0; rf < 4; ++rf)
            acc[cf][rf] = (f32x4){0.f, 0.f, 0.f, 0.f};

    #pragma unroll
    for (int kk = 0; kk < 4; ++kk) {
        bf16x8 a[4], b[4];
        #pragma unroll
        for (int cf = 0; cf < 4; ++cf)
            a[cf] = *(const bf16x8*)(w1abt + (w * 64 + cf * 16 + l15) * 128 + kk * 32 + lq * 8);
        #pragma unroll
        for (int rf = 0; rf < 4; ++rf) {
            int row = rf * 16 + l15;
            a[0] = a[0]; // keep order
            b[rf] = *(const bf16x8*)((const char*)A + row * 256 + ((kk * 64 + lq * 16) ^ ((row & 7) << 4)));
        }
        #pragma unroll
        for (int cf = 0; cf < 4; ++cf)
            #pragma unroll
            for (int rf = 0; rf < 4; ++rf)
                acc[cf][rf] = __builtin_amdgcn_mfma_f32_16x16x32_bf16(a[cf], b[rf], acc[cf][rf], 0, 0, 0);
    }

    // D[ch][node]: node = rf*16 + l15 (lane), ch = w*64 + cf*16 + lq*4 + r (regs) -> pack 4 ch -> ushort4
    #pragma unroll
    for (int rf = 0; rf < 4; ++rf) {
        int node = base + rf * 16 + l15;
        if (node < n_nodes) {
            #pragma unroll
            for (int cf = 0; cf < 4; ++cf) {
                int ch = w * 64 + cf * 16 + lq * 4;
                ushort4 o;
                o.x = f2bf(acc[cf][rf][0]);
                o.y = f2bf(acc[cf][rf][1]);
                o.z = f2bf(acc[cf][rf][2]);
                o.w = f2bf(acc[cf][rf][3]);
                *(ushort4*)(pab + (size_t)node * NCH + ch) = o;
            }
        }
    }
}

// ---------- hierarchical exclusive scan (coalesced)
__global__ void scan1_kernel(const int* __restrict__ hist, int* __restrict__ partial, int N)
{
    __shared__ int s[256];
    int tid = threadIdx.x;
    int i = blockIdx.x * 256 + tid;
    s[tid] = (i < N) ? hist[i] : 0;
    __syncthreads();
    #pragma unroll
    for (int off = 128; off > 0; off >>= 1) {
        if (tid < off) s[tid] += s[tid + off];
        __syncthreads();
    }
    if (tid == 0) partial[blockIdx.x] = s[0];
}

__global__ void scan2_kernel(const int* __restrict__ partial, int* __restrict__ bofs, int nb)
{
    __shared__ int s[256];
    int tid = threadIdx.x;
    int v = (tid < nb) ? partial[tid] : 0;
    s[tid] = v;
    __syncthreads();
    #pragma unroll
    for (int off = 1; off < 256; off <<= 1) {
        int t = (tid >= off) ? s[tid - off] : 0;
        __syncthreads();
        s[tid] += t;
        __syncthreads();
    }
    if (tid < nb) bofs[tid] = s[tid] - v;
}

__global__ void scan3_kernel(const int* __restrict__ hist, const int* __restrict__ bofs,
                             int* __restrict__ ofs, int N)
{
    __shared__ int s[256];
    int tid = threadIdx.x;
    int i = blockIdx.x * 256 + tid;
    int v = (i < N) ? hist[i] : 0;
    s[tid] = v;
    __syncthreads();
    #pragma unroll
    for (int off = 1; off < 256; off <<= 1) {
        int t = (tid >= off) ? s[tid - off] : 0;
        __syncthreads();
        s[tid] += t;
        __syncthreads();
    }
    if (i < N) ofs[i] = bofs[blockIdx.x] + s[tid] - v;
}

// ---------- scatter: counting sort; emit (col,row) pairs directly (coalesced consumption)
__global__ void scatter_kernel(const int* __restrict__ erow, const int* __restrict__ ecol,
                               int* __restrict__ ofs,
                               int* __restrict__ scol, int* __restrict__ srow,
                               int E, int n_nodes)
{
    int e = blockIdx.x * blockDim.x + threadIdx.x;
    if (e < E) {
        int c = ecol[e];
        if ((unsigned)c >= (unsigned)n_nodes) c = 0;
        int r = erow[e];
        if ((unsigned)r >= (unsigned)n_nodes) r = 0;
        int pos = atomicAdd(&ofs[c], 1);
        scol[pos] = c;
        srow[pos] = r;
    }
}

// ---------- main fused kernel: 64 sorted edges per block, 256 threads (4 waves, 2x2)
__global__ __launch_bounds__(256, 4) void edgeconv_main(
    const ushort* __restrict__ pab,
    const ushort* __restrict__ w2t,
    const float* __restrict__ b1,
    const float* __restrict__ b2,
    const int* __restrict__ scol,
    const int* __restrict__ srow,
    unsigned int* __restrict__ out_enc,
    int E, int n_nodes)
{
    __shared__ char smem[64 * 256];     // 16KB: Hs bf16[64][128] (swizzled), then Mf f32[64][64] halves
    __shared__ float bias1s[128];
    __shared__ float bias2s[128];
    __shared__ int colidx[64];
    __shared__ int rowidx[64];
    __shared__ unsigned char starts[64];
    __shared__ int nruns_s, nvalid_s;

    const int tid = threadIdx.x;

    // XCD-bijective swizzle: consecutive sorted tiles -> same XCD L2
    const int nwg = gridDim.x, orig = blockIdx.x;
    const int q = nwg >> 3, rr = nwg & 7, xcd = orig & 7;
    const int wgid = (xcd < rr ? xcd * (q + 1) : rr * (q + 1) + (xcd - rr) * q) + (orig >> 3);
    const int e0 = wgid * 64;

    if (tid < 128) bias1s[tid] = b1[tid];
    else           bias2s[tid - 128] = b2[tid - 128];
    if (tid < 64) {
        int idx = e0 + tid;
        colidx[tid] = (idx < E) ? scol[idx] : -1;
        rowidx[tid] = (idx < E) ? srow[idx] : 0;
    }
    __syncthreads();

    if (tid < 64) {
        int c = colidx[tid];
        bool valid = (c >= 0);
        bool isStart = valid && (tid == 0 || colidx[tid - 1] != c);
        unsigned long long mb = __ballot(isStart);
        unsigned long long vb = __ballot(valid);
        if (tid == 0) { nruns_s = __popcll(mb); nvalid_s = __popcll(vb); }
        if (isStart) starts[__popcll(mb & ((1ull << tid) - 1ull))] = (unsigned char)tid;
    }

    // ---- phase 1: h = relu(Pa[col] + Pb[row] + b1) -> Hs (bf16, swizzled)
    ushort* Hs = (ushort*)smem;
    {
        const int cg   = tid & 15;      // 16 threads per edge -> coalesced 256B per side
        const int esub = tid >> 4;
        float bb[8];
        #pragma unroll
        for (int j = 0; j < 8; ++j) bb[j] = bias1s[cg * 8 + j];

        bf16x8 va[4], vb[4];
        #pragma unroll
        for (int it = 0; it < 4; ++it) {
            int e = it * 16 + esub;
            int c = colidx[e]; if (c < 0) c = 0;
            int r = rowidx[e];
            va[it] = *(const bf16x8*)(pab + (size_t)c * NCH + cg * 8);
            vb[it] = *(const bf16x8*)(pab + (size_t)r * NCH + 128 + cg * 8);
        }
        #pragma unroll
        for (int it = 0; it < 4; ++it) {
            int e = it * 16 + esub;
            bf16x8 vh;
            #pragma unroll
            for (int j = 0; j < 8; ++j) {
                float f = bf2f((ushort)va[it][j]) + bf2f((ushort)vb[it][j]) + bb[j];
                f = fmaxf(f, 0.f);
                vh[j] = (short)f2bf(f);
            }
            *(bf16x8*)((char*)Hs + e * 256 + ((cg * 16) ^ ((e & 7) << 4))) = vh;
        }
    }
    __syncthreads();

    const int l = tid & 63, w = tid >> 6;
    const int wr = w >> 1, wc = w & 1;
    const int l15 = l & 15, lq = l >> 4;
    const int mr = wr * 32;

    // ---- layer 2: [64x128] @ [128x128] -> msg
    f32x4 acc2[2][4];
    #pragma unroll
    for (int mf = 0; mf < 2; ++mf)
        #pragma unroll
        for (int nf = 0; nf < 4; ++nf)
            acc2[mf][nf] = (f32x4){0.f, 0.f, 0.f, 0.f};

    #pragma unroll
    for (int kk = 0; kk < 4; ++kk) {
        bf16x8 a[2], b[4];
        #pragma unroll
        for (int mf = 0; mf < 2; ++mf) {
            int row = mr + mf * 16 + l15;
            a[mf] = *(const bf16x8*)((const char*)Hs + row * 256 + ((kk * 64 + lq * 16) ^ ((row & 7) << 4)));
        }
        #pragma unroll
        for (int nf = 0; nf < 4; ++nf) {
            int wcol = wc * 64 + nf * 16 + l15;
            b[nf] = *(const bf16x8*)(w2t + wcol * 128 + kk * 32 + lq * 8);
        }
        #pragma unroll
        for (int mf = 0; mf < 2; ++mf)
            #pragma unroll
            for (int nf = 0; nf < 4; ++nf)
                acc2[mf][nf] = __builtin_amdgcn_mfma_f32_16x16x32_bf16(a[mf], b[nf], acc2[mf][nf], 0, 0, 0);
    }

    float b2c[4];
    #pragma unroll
    for (int nf = 0; nf < 4; ++nf) b2c[nf] = bias2s[wc * 64 + nf * 16 + l15];

    // ---- two col-halves: stage M (f32, swizzled, overlaying Hs), segmented max, atomic per (run,col)
    float* Mf = (float*)smem;
    #pragma unroll
    for (int half = 0; half < 2; ++half) {
        __syncthreads();                 // all reads of smem from previous phase done
        if (wc == half) {
            #pragma unroll
            for (int nf = 0; nf < 4; ++nf)
                #pragma unroll
                for (int mf = 0; mf < 2; ++mf)
                    #pragma unroll
                    for (int r = 0; r < 4; ++r) {
                        int row = mr + mf * 16 + lq * 4 + r;
                        int cl = nf * 16 + l15;
                        *(float*)((char*)Mf + row * 256 + ((cl * 4) ^ ((row & 7) << 4))) =
                            acc2[mf][nf][r] + b2c[nf];
                    }
        }
        __syncthreads();
        {
            const int c = tid & 63, g = tid >> 6;
            const int nruns = nruns_s, nvalid = nvalid_s;
            for (int k = g; k < nruns; k += 4) {
                int s  = starts[k];
                int e_ = (k + 1 < nruns) ? (int)starts[k + 1] : nvalid;
                float m = -INFINITY;
                for (int r2 = s; r2 < e_; ++r2)
                    m = fmaxf(m, *(const float*)((const char*)Mf + r2 * 256 + ((c * 4) ^ ((r2 & 7) << 4))));
                int node = colidx[s];
                unsigned bs = __float_as_uint(m);
                unsigned enc = (bs & 0x80000000u) ? ~bs : (bs | 0x80000000u);
                atomicMax(&out_enc[(size_t)node * D + half * 64 + c], enc);
            }
        }
    }
}

// ---------- decode: in-place on d_out; u==0 means empty segment -> 0.0f
__global__ void decode_kernel(unsigned int* __restrict__ io, int n4)
{
    int gid = blockIdx.x * blockDim.x + threadIdx.x;
    if (gid < n4) {
        uint4 u = ((const uint4*)io)[gid];
        float4 f;
        #define DEC(ux) ((ux) == 0u ? 0.f : (((ux) & 0x80000000u) ? __uint_as_float((ux) & 0x7fffffffu) : __uint_as_float(~(ux))))
        f.x = DEC(u.x); f.y = DEC(u.y); f.z = DEC(u.z); f.w = DEC(u.w);
        #undef DEC
        ((float4*)io)[gid] = f;
    }
}

extern "C" void kernel_launch(void* const* d_in, const int* in_sizes, int n_in,
                              void* d_out, int out_size, void* d_ws, size_t ws_size,
                              hipStream_t stream)
{
    const float* x  = (const float*)d_in[0];
    const int* eidx = (const int*)d_in[1];
    const float* W1 = (const float*)d_in[2];
    const float* b1 = (const float*)d_in[3];
    const float* W2 = (const float*)d_in[4];
    const float* b2 = (const float*)d_in[5];

    const int n_nodes = in_sizes[0] / D;
    const int E = in_sizes[1] / 2;
    const int* erow = eidx;        // edge_index[0]
    const int* ecol = eidx + E;    // edge_index[1]

    // ---- workspace layout
    char* ws = (char*)d_ws;
    size_t off = 0;
    ushort* pab = (ushort*)(ws + off);   off += (size_t)n_nodes * NCH * sizeof(ushort);
    off = (off + 255) & ~(size_t)255;
    ushort* w1abt = (ushort*)(ws + off); off += (size_t)NCH * D * sizeof(ushort);
    ushort* w2t = (ushort*)(ws + off);   off += (size_t)D * D * sizeof(ushort);
    off = (off + 255) & ~(size_t)255;
    int* hist = (int*)(ws + off);        off += (size_t)n_nodes * 4;
    off = (off + 255) & ~(size_t)255;
    int* ofs = (int*)(ws + off);         off += (size_t)n_nodes * 4;
    off = (off + 255) & ~(size_t)255;
    int* partial = (int*)(ws + off);     off += 256 * 4;
    int* bofs = (int*)(ws + off);        off += 256 * 4;
    off = (off + 255) & ~(size_t)255;
    int* scol = (int*)(ws + off);        off += (size_t)E * 4;
    int* srow = (int*)(ws + off);        off += (size_t)E * 4;

    unsigned int* out_enc = (unsigned int*)d_out;

    hipMemsetAsync(d_out, 0, (size_t)out_size * sizeof(float), stream);
    hipMemsetAsync(hist, 0, (size_t)n_nodes * sizeof(int), stream);

    const int prep_work = NCH * D + D * D + E;
    prep_kernel<<<(prep_work + 255) / 256, 256, 0, stream>>>(W1, W2, ecol, w1abt, w2t, hist, E, n_nodes);

    const int nb = (n_nodes + 255) / 256;   // 196 <= 256
    scan1_kernel<<<nb, 256, 0, stream>>>(hist, partial, n_nodes);
    scan2_kernel<<<1, 256, 0, stream>>>(partial, bofs, nb);
    scan3_kernel<<<nb, 256, 0, stream>>>(hist, bofs, ofs, n_nodes);

    scatter_kernel<<<(E + 255) / 256, 256, 0, stream>>>(erow, ecol, ofs, scol, srow, E, n_nodes);

    pab_kernel<<<(n_nodes + 63) / 64, 256, 0, stream>>>(x, w1abt, pab, n_nodes);

    const int nblocks = (E + 63) / 64;
    edgeconv_main<<<nblocks, 256, 0, stream>>>(pab, w2t, b1, b2, scol, srow, out_enc, E, n_nodes);

    const int n4 = out_size / 4;
    decode_kernel<<<(n4 + 255) / 256, 256, 0, stream>>>(out_enc, n4);
}